// Round 18
// baseline (908.393 us; speedup 1.0000x reference)
//
#include <hip/hip_runtime.h>
#include <hip/hip_bf16.h>

// B=16, N=256, P=8, D=512, H=8, E=4096, dh=512, scale=1/8. Outputs fp32.
// Round 18: continue the proven occupancy lever (r15/r17: co-resident blocks
// > pipelining). gemmc_nt: 128x128 tile, 256 thr (4 waves of 64x64 -- same
// per-wave work & swizzle/sync skeleton as r17's gemm4), 32 KiB LDS ->
// grid 1024 = 4 blocks/CU. Plus f16 pos table (halves embed's scattered
// epilogue reads; |pos|<~0.3 so f16 rounding is noise).
// Attention + converts unchanged (validated r13-r17).

typedef unsigned short u16;
typedef _Float16 f16;
typedef __attribute__((ext_vector_type(8))) _Float16 v8h;    // 8 f16 = 4 VGPR
typedef __attribute__((ext_vector_type(8))) short vu16x8;    // raw 16B
typedef __attribute__((ext_vector_type(4))) float vf32x4;    // MFMA acc

#define MFMA_F16(a, b, c) __builtin_amdgcn_mfma_f32_16x16x32_f16(a, b, c, 0, 0, 0)

__device__ __forceinline__ void gld16(const void* g, void* l) {
    // async global->LDS, 16B/lane; LDS dest = wave-uniform base + lane*16
    __builtin_amdgcn_global_load_lds((const __attribute__((address_space(1))) void*)g,
                                     (__attribute__((address_space(3))) void*)l,
                                     16, 0, 0);
}

// ---------------- fp32 -> f16 ------------------------------------------------
__global__ __launch_bounds__(256) void tof16(const float* __restrict__ s,
                                             f16* __restrict__ d) {
    const size_t i = ((size_t)blockIdx.x * 256 + threadIdx.x) * 4;
    const float4 v = *(const float4*)(s + i);
    d[i + 0] = (f16)v.x; d[i + 1] = (f16)v.y;
    d[i + 2] = (f16)v.z; d[i + 3] = (f16)v.w;
}

// ---------------- 128x128 single-buffer f16 NT GEMM (all projections) -------
// 256 thr = 4 waves (2M x 2N), per-wave 64x64 out = 4x4 frags. BK=64.
// 32 KiB LDS, grid 1024 -> 4 blocks/CU; cross-block overlap hides staging.
// MODE 0: +bias +pos(f16) -> f16 ; MODE 1: +bias -> f16 ; MODE 2: -> fp32.
template <int MODE>
__global__ __launch_bounds__(256, 4)
void gemmc_nt(const f16* __restrict__ A, const f16* __restrict__ Bw,
              const float* __restrict__ bias, const f16* __restrict__ posh,
              f16* __restrict__ Ch, float* __restrict__ Cf) {
    __shared__ __align__(16) u16 sA[8192];       // 128 rows x 64 f16, swizzled
    __shared__ __align__(16) u16 sB[8192];       // 128 rows x 64 f16, swizzled
    const int t = threadIdx.x;
    const int lane = t & 63, w = t >> 6;
    const int wm = w >> 1, wn = w & 1;           // 2 x 2 wave grid
    const int l15 = lane & 15, lg = lane >> 4;
    // XCD-chunked swizzle: 1024 blocks, 128 contiguous per XCD (bijective)
    const int wg = ((blockIdx.x & 7) << 7) + (blockIdx.x >> 3);
    const int m0 = (wg >> 5) << 7, n0 = (wg & 31) << 7;

    // staging maps (A,B: 1024 chunks each = 4/thread each)
    int aRow[4], aCol[4];
#pragma unroll
    for (int i = 0; i < 4; ++i) {
        const int c = t + (i << 8);
        aRow[i] = c >> 3;                        // 0..127
        aCol[i] = (((c & 7) ^ (aRow[i] & 7)) << 3);
    }
    const int rA = (wm << 6) + l15;              // A row base (within 128)
    const int rB = (wn << 6) + l15;              // B row base (within 128)
    const int xA = rA & 7, xB = rB & 7;          // row&7 invariant under +m*16

    vf32x4 acc[4][4] = {};

    for (int kt = 0; kt < 64; ++kt) {
        const int k0 = kt << 6;
#pragma unroll
        for (int i = 0; i < 4; ++i) {
            const int c = t + (i << 8);
            gld16(A  + (((size_t)(m0 + aRow[i])) << 12) + k0 + aCol[i],
                  &sA[c * 8]);
            gld16(Bw + (((size_t)(n0 + aRow[i])) << 12) + k0 + aCol[i],
                  &sB[c * 8]);
        }
        asm volatile("s_waitcnt vmcnt(0)" ::: "memory");
        __builtin_amdgcn_s_barrier();            // tile landed for all waves
        asm volatile("" ::: "memory");
#pragma unroll
        for (int kk = 0; kk < 2; ++kk) {
            const int ccA = (((kk << 2) + lg) ^ xA) << 3;
            const int ccB = (((kk << 2) + lg) ^ xB) << 3;
            v8h av[4], bv[4];
#pragma unroll
            for (int m = 0; m < 4; ++m)
                av[m] = *(const v8h*)(&sA[((rA + (m << 4)) << 6) + ccA]);
#pragma unroll
            for (int n = 0; n < 4; ++n)
                bv[n] = *(const v8h*)(&sB[((rB + (n << 4)) << 6) + ccB]);
            asm volatile("s_waitcnt lgkmcnt(0)" ::: "memory");
            __builtin_amdgcn_sched_barrier(0);
            __builtin_amdgcn_s_setprio(1);
#pragma unroll
            for (int m = 0; m < 4; ++m)
#pragma unroll
                for (int n = 0; n < 4; ++n)
                    acc[m][n] = MFMA_F16(av[m], bv[n], acc[m][n]);
            __builtin_amdgcn_s_setprio(0);
        }
        __builtin_amdgcn_s_barrier();            // all reads done before next
        asm volatile("" ::: "memory");           // iteration's STAGE overwrites
    }

#pragma unroll
    for (int n = 0; n < 4; ++n) {
        const int col = n0 + (wn << 6) + (n << 4) + l15;
        const float bvv = bias[col];
#pragma unroll
        for (int m = 0; m < 4; ++m) {
#pragma unroll
            for (int r = 0; r < 4; ++r) {
                const int row = m0 + (wm << 6) + (m << 4) + (lg << 2) + r;
                float v = acc[m][n][r] + bvv;
                if (MODE == 0)
                    v += (float)posh[((size_t)(row & 255) << 12) + col];
                if (MODE == 2)
                    Cf[((size_t)row << 12) + col] = v;
                else
                    Ch[((size_t)row << 12) + col] = (f16)v;
            }
        }
    }
}

// ---------------- f16 scores + softmax -> P fp32 (out1) + P f16 (PV) --------
// grid = 512: XCD-contiguous remap (4 q-slab blocks of one (b,h) share K).
__global__ __launch_bounds__(256)
void attn_scores(const f16* __restrict__ q, const f16* __restrict__ k,
                 float* __restrict__ Pf, f16* __restrict__ Pb) {
    const int blk = ((blockIdx.x & 7) << 6) + (blockIdx.x >> 3);  // 8 XCDs x 64
    const int bh = blk >> 2, it = blk & 3;
    const int b = bh >> 3, h = bh & 7;
    const size_t qoff = ((size_t)(b * 256 + it * 64) << 12) + (h << 9);
    const size_t koff = ((size_t)(b * 256) << 12) + (h << 9);
    __shared__ __align__(16) u16 Qs[64 * 64];
    __shared__ __align__(16) u16 Ks[256 * 64];
    __shared__ float red[4][64];

    const int t = threadIdx.x;
    const int lane = t & 63, w = t >> 6;
    const int l15 = lane & 15, lg = lane >> 4;

    vf32x4 acc[4][4] = {};

    for (int k0 = 0; k0 < 512; k0 += 64) {
#pragma unroll
        for (int i = 0; i < 2; ++i) {               // Q slab: 64x64
            const int c = t + (i << 8);
            const int row = c >> 3, c8 = (c & 7) << 3;
            gld16(q + qoff + ((size_t)row << 12) + k0 + c8, Qs + c * 8);
        }
#pragma unroll
        for (int i = 0; i < 8; ++i) {               // K: 256x64
            const int c = t + (i << 8);
            const int row = c >> 3, c8 = (c & 7) << 3;
            gld16(k + koff + ((size_t)row << 12) + k0 + c8, Ks + c * 8);
        }
        __syncthreads();
#pragma unroll
        for (int kk = 0; kk < 2; ++kk) {
            v8h af[4], bf[4];
#pragma unroll
            for (int m = 0; m < 4; ++m)
                af[m] = *(const v8h*)(Qs + (m * 16 + l15) * 64 + kk * 32 + lg * 8);
#pragma unroll
            for (int n = 0; n < 4; ++n)
                bf[n] = *(const v8h*)(Ks + (w * 64 + n * 16 + l15) * 64 + kk * 32 + lg * 8);
#pragma unroll
            for (int m = 0; m < 4; ++m)
#pragma unroll
                for (int n = 0; n < 4; ++n)
                    acc[m][n] = MFMA_F16(af[m], bf[n], acc[m][n]);
        }
        __syncthreads();
    }

#pragma unroll
    for (int m = 0; m < 4; ++m)
#pragma unroll
        for (int n = 0; n < 4; ++n) acc[m][n] *= 0.125f;

    float gm[4][4];
#pragma unroll
    for (int m = 0; m < 4; ++m)
#pragma unroll
        for (int r = 0; r < 4; ++r) {
            float v = fmaxf(fmaxf(acc[m][0][r], acc[m][1][r]),
                            fmaxf(acc[m][2][r], acc[m][3][r]));
#pragma unroll
            for (int off = 1; off < 16; off <<= 1) v = fmaxf(v, __shfl_xor(v, off));
            gm[m][r] = v;
        }
    if (l15 == 0) {
#pragma unroll
        for (int m = 0; m < 4; ++m)
#pragma unroll
            for (int r = 0; r < 4; ++r) red[w][m * 16 + lg * 4 + r] = gm[m][r];
    }
    __syncthreads();
#pragma unroll
    for (int m = 0; m < 4; ++m)
#pragma unroll
        for (int r = 0; r < 4; ++r) {
            const int row = m * 16 + lg * 4 + r;
            gm[m][r] = fmaxf(fmaxf(red[0][row], red[1][row]),
                             fmaxf(red[2][row], red[3][row]));
        }
    __syncthreads();

    float gs[4][4];
#pragma unroll
    for (int m = 0; m < 4; ++m)
#pragma unroll
        for (int r = 0; r < 4; ++r) {
            float s = 0.f;
#pragma unroll
            for (int n = 0; n < 4; ++n) {
                const float e = __expf(acc[m][n][r] - gm[m][r]);
                acc[m][n][r] = e;
                s += e;
            }
#pragma unroll
            for (int off = 1; off < 16; off <<= 1) s += __shfl_xor(s, off);
            gs[m][r] = s;
        }
    if (l15 == 0) {
#pragma unroll
        for (int m = 0; m < 4; ++m)
#pragma unroll
            for (int r = 0; r < 4; ++r) red[w][m * 16 + lg * 4 + r] = gs[m][r];
    }
    __syncthreads();

    const size_t pbase = ((size_t)bh * 256 + it * 64) * 256;
#pragma unroll
    for (int m = 0; m < 4; ++m)
#pragma unroll
        for (int r = 0; r < 4; ++r) {
            const int row = m * 16 + lg * 4 + r;
            const float inv = 1.0f / (red[0][row] + red[1][row] +
                                      red[2][row] + red[3][row]);
#pragma unroll
            for (int n = 0; n < 4; ++n) {
                const int col = w * 64 + n * 16 + l15;
                const float p = acc[m][n][r] * inv;
                Pf[pbase + (size_t)row * 256 + col] = p;
                Pb[pbase + (size_t)row * 256 + col] = (f16)p;
            }
        }
}

// ---------------- PV: ao[b,n,h*512+j] = sum_m P[b,h,n,m] * v[b,m,h*512+j] ---
__global__ __launch_bounds__(256)
void attn_pv(const f16* __restrict__ P, const f16* __restrict__ V,
             f16* __restrict__ O) {
    __shared__ __align__(16) u16 Ps[128 * 64];
    __shared__ __align__(16) u16 Vt[128 * 72];   // [j][m], padded stride 72
    const int t = threadIdx.x;
    const int lane = t & 63, w = t >> 6;
    const int wr = (w >> 1) << 6, wc = (w & 1) << 6;
    const int l15 = lane & 15, lg = lane >> 4;
    const int blk = ((blockIdx.x & 7) << 7) + (blockIdx.x >> 3);  // 8 x 128
    const int bh = blk >> 3, mt = (blk >> 2) & 1, nt = blk & 3;
    const int b = bh >> 3, h = bh & 7;
    const f16* Pbp = P + ((size_t)bh << 16) + ((size_t)mt << 15);
    const u16* Vb = (const u16*)V + ((size_t)(b * 256) << 12) + (h << 9) + (nt << 7);

    vf32x4 acc[4][4] = {};

    for (int k0 = 0; k0 < 256; k0 += 64) {
#pragma unroll
        for (int i = 0; i < 4; ++i) {               // P tile 128x64, linear
            const int c = t + (i << 8);
            const int row = c >> 3, c8 = (c & 7) << 3;
            gld16(Pbp + (size_t)row * 256 + k0 + c8, Ps + c * 8);
        }
#pragma unroll
        for (int pp = 0; pp < 4; ++pp) {            // V tile 64x128, transposed
            const int kr = pp * 16 + (t >> 4);
            const int c8 = (t & 15) << 3;
            vu16x8 vv = *(const vu16x8*)(Vb + ((size_t)(k0 + kr) << 12) + c8);
#pragma unroll
            for (int c = 0; c < 8; ++c) Vt[(c8 + c) * 72 + kr] = (u16)vv[c];
        }
        __syncthreads();
#pragma unroll
        for (int kk = 0; kk < 2; ++kk) {
            v8h af[4], bf[4];
#pragma unroll
            for (int m = 0; m < 4; ++m)
                af[m] = *(const v8h*)(Ps + (wr + m * 16 + l15) * 64 + kk * 32 + lg * 8);
#pragma unroll
            for (int n = 0; n < 4; ++n)
                bf[n] = *(const v8h*)(Vt + (wc + n * 16 + l15) * 72 + kk * 32 + lg * 8);
#pragma unroll
            for (int m = 0; m < 4; ++m)
#pragma unroll
                for (int n = 0; n < 4; ++n)
                    acc[m][n] = MFMA_F16(af[m], bf[n], acc[m][n]);
        }
        __syncthreads();
    }

#pragma unroll
    for (int m = 0; m < 4; ++m)
#pragma unroll
        for (int n = 0; n < 4; ++n) {
            const int col = (h << 9) + (nt << 7) + wc + n * 16 + l15;
#pragma unroll
            for (int r = 0; r < 4; ++r) {
                const int row = b * 256 + mt * 128 + wr + m * 16 + lg * 4 + r;
                O[((size_t)row << 12) + col] = (f16)acc[m][n][r];
            }
        }
}

// ---------------------------------------------------------------------------
extern "C" void kernel_launch(void* const* d_in, const int* in_sizes, int n_in,
                              void* d_out, int out_size, void* d_ws, size_t ws_size,
                              hipStream_t stream) {
    const float* x   = (const float*)d_in[0];
    const float* pos = (const float*)d_in[1];
    const float* wE  = (const float*)d_in[2];
    const float* bE  = (const float*)d_in[3];
    const float* wQ  = (const float*)d_in[4];
    const float* bq  = (const float*)d_in[5];
    const float* wK  = (const float*)d_in[6];
    const float* bk  = (const float*)d_in[7];
    const float* wV  = (const float*)d_in[8];
    const float* bv  = (const float*)d_in[9];
    const float* wO  = (const float*)d_in[10];
    const float* bo  = (const float*)d_in[11];

    float* out  = (float*)d_out;                    // output 0: 16,777,216 fp32
    float* Pout = out + (size_t)16777216;           // output 1:  8,388,608 fp32

    // ws layout (MiB offsets), peak 212 MiB
    char* W = (char*)d_ws;
    const size_t MB = 1024 * 1024;
    f16* xf    = (f16*)(W + 0 * MB);     // x f16; later ao (x dead post-embed)
    f16* wslab = (f16*)(W + 32 * MB);    // current weight f16
    f16* xe    = (f16*)(W + 64 * MB);    // embedded activations f16
    f16* qs    = (f16*)(W + 96 * MB);    // Q f16
    f16* ks    = (f16*)(W + 128 * MB);   // K f16
    f16* vs    = (f16*)(W + 160 * MB);   // V f16
    f16* Pb    = (f16*)(W + 192 * MB);   // P f16 (16 MiB)
    f16* posh  = (f16*)(W + 208 * MB);   // pos f16 (2 MiB)
    f16* ao    = xf;                     // PV result over x (dead)

    const int CVG = 16384;   // 16.7M elems / (256 thr * 4/thread)
    const int CVP = 1024;    // 1,048,576 pos elems / (256 * 4)

    tof16<<<CVP, 256, 0, stream>>>(pos, posh);
    tof16<<<CVG, 256, 0, stream>>>(x, xf);
    tof16<<<CVG, 256, 0, stream>>>(wE, wslab);
    gemmc_nt<0><<<1024, 256, 0, stream>>>(xf, wslab, bE, posh, xe, nullptr);

    tof16<<<CVG, 256, 0, stream>>>(wQ, wslab);
    gemmc_nt<1><<<1024, 256, 0, stream>>>(xe, wslab, bq, nullptr, qs, nullptr);

    tof16<<<CVG, 256, 0, stream>>>(wK, wslab);
    gemmc_nt<1><<<1024, 256, 0, stream>>>(xe, wslab, bk, nullptr, ks, nullptr);

    tof16<<<CVG, 256, 0, stream>>>(wV, wslab);
    gemmc_nt<1><<<1024, 256, 0, stream>>>(xe, wslab, bv, nullptr, vs, nullptr);

    attn_scores<<<512, 256, 0, stream>>>(qs, ks, Pout, Pb);
    attn_pv<<<1024, 256, 0, stream>>>(Pb, vs, ao);

    tof16<<<CVG, 256, 0, stream>>>(wO, wslab);
    gemmc_nt<2><<<1024, 256, 0, stream>>>(ao, wslab, bo, nullptr, nullptr, out);
}

// Round 19
// 810.637 us; speedup vs baseline: 1.1206x; 1.1206x over previous
//
#include <hip/hip_runtime.h>
#include <hip/hip_bf16.h>

// B=16, N=256, P=8, D=512, H=8, E=4096, dh=512, scale=1/8. Outputs fp32.
// Round 19: consolidation to measured optimum. r17 verbatim (820us best:
// 256x128 tile, single-buffer 48KiB, 512 blocks = 2 blocks/CU -- the pareto
// point: r16 dbuf@BK=32 = 915, r18 128^2@4/CU = 908 w/ 2x FETCH) plus r18's
// validated f16 pos table (halves embed's scattered epilogue reads; absmax
// unchanged at grid floor). Attention + converts unchanged (r13-r18).

typedef unsigned short u16;
typedef _Float16 f16;
typedef __attribute__((ext_vector_type(8))) _Float16 v8h;    // 8 f16 = 4 VGPR
typedef __attribute__((ext_vector_type(8))) short vu16x8;    // raw 16B
typedef __attribute__((ext_vector_type(4))) float vf32x4;    // MFMA acc

#define MFMA_F16(a, b, c) __builtin_amdgcn_mfma_f32_16x16x32_f16(a, b, c, 0, 0, 0)

__device__ __forceinline__ void gld16(const void* g, void* l) {
    // async global->LDS, 16B/lane; LDS dest = wave-uniform base + lane*16
    __builtin_amdgcn_global_load_lds((const __attribute__((address_space(1))) void*)g,
                                     (__attribute__((address_space(3))) void*)l,
                                     16, 0, 0);
}

// ---------------- fp32 -> f16 ------------------------------------------------
__global__ __launch_bounds__(256) void tof16(const float* __restrict__ s,
                                             f16* __restrict__ d) {
    const size_t i = ((size_t)blockIdx.x * 256 + threadIdx.x) * 4;
    const float4 v = *(const float4*)(s + i);
    d[i + 0] = (f16)v.x; d[i + 1] = (f16)v.y;
    d[i + 2] = (f16)v.z; d[i + 3] = (f16)v.w;
}

// ---------------- 256x128 single-buffer f16 NT GEMM (all projections) -------
// 512 thr = 8 waves (4M x 2N), per-wave 64x64 out = 4x4 frags. BK=64.
// 48 KiB LDS, 512 blocks -> 2 blocks/CU; cross-block overlap hides staging.
// MODE 0: +bias +pos(f16) -> f16 ; MODE 1: +bias -> f16 ; MODE 2: -> fp32.
template <int MODE>
__global__ __launch_bounds__(512, 4)
void gemm4_nt(const f16* __restrict__ A, const f16* __restrict__ Bw,
              const float* __restrict__ bias, const f16* __restrict__ posh,
              f16* __restrict__ Ch, float* __restrict__ Cf) {
    __shared__ __align__(16) u16 sA[16384];      // 256 rows x 64 f16, swizzled
    __shared__ __align__(16) u16 sB[8192];       // 128 rows x 64 f16, swizzled
    const int t = threadIdx.x;
    const int lane = t & 63, w = t >> 6;
    const int wm = w >> 1, wn = w & 1;           // 4 x 2 wave grid
    const int l15 = lane & 15, lg = lane >> 4;
    // XCD-chunked swizzle: 512 blocks, 64 contiguous per XCD (bijective)
    const int wg = ((blockIdx.x & 7) << 6) + (blockIdx.x >> 3);
    const int m0 = (wg >> 5) << 8, n0 = (wg & 31) << 7;

    // staging maps (A: 2048 chunks = 4/thread; B: 1024 chunks = 2/thread)
    int aRow[4], aCol[4], bRow[2], bCol[2];
#pragma unroll
    for (int i = 0; i < 4; ++i) {
        const int c = t + (i << 9);
        aRow[i] = c >> 3;
        aCol[i] = (((c & 7) ^ (aRow[i] & 7)) << 3);
    }
#pragma unroll
    for (int i = 0; i < 2; ++i) {
        const int c = t + (i << 9);
        bRow[i] = c >> 3;
        bCol[i] = (((c & 7) ^ (bRow[i] & 7)) << 3);
    }
    const int rA = (wm << 6) + l15;              // A row (within 256)
    const int rB = (wn << 6) + l15;              // B row (within 128)
    const int xA = rA & 7, xB = rB & 7;          // row&7 invariant under +m*16

    vf32x4 acc[4][4] = {};

    for (int kt = 0; kt < 64; ++kt) {
        const int k0 = kt << 6;
#pragma unroll
        for (int i = 0; i < 4; ++i) {
            const int c = t + (i << 9);
            gld16(A + (((size_t)(m0 + aRow[i])) << 12) + k0 + aCol[i],
                  &sA[c * 8]);
        }
#pragma unroll
        for (int i = 0; i < 2; ++i) {
            const int c = t + (i << 9);
            gld16(Bw + (((size_t)(n0 + bRow[i])) << 12) + k0 + bCol[i],
                  &sB[c * 8]);
        }
        asm volatile("s_waitcnt vmcnt(0)" ::: "memory");
        __builtin_amdgcn_s_barrier();            // tile landed for all waves
        asm volatile("" ::: "memory");
#pragma unroll
        for (int kk = 0; kk < 2; ++kk) {
            const int ccA = (((kk << 2) + lg) ^ xA) << 3;
            const int ccB = (((kk << 2) + lg) ^ xB) << 3;
            v8h av[4], bv[4];
#pragma unroll
            for (int m = 0; m < 4; ++m)
                av[m] = *(const v8h*)(&sA[(rA << 6) + (m << 10) + ccA]);
#pragma unroll
            for (int n = 0; n < 4; ++n)
                bv[n] = *(const v8h*)(&sB[(rB << 6) + (n << 10) + ccB]);
            asm volatile("s_waitcnt lgkmcnt(0)" ::: "memory");
            __builtin_amdgcn_sched_barrier(0);
            __builtin_amdgcn_s_setprio(1);
#pragma unroll
            for (int m = 0; m < 4; ++m)
#pragma unroll
                for (int n = 0; n < 4; ++n)
                    acc[m][n] = MFMA_F16(av[m], bv[n], acc[m][n]);
            __builtin_amdgcn_s_setprio(0);
        }
        __builtin_amdgcn_s_barrier();            // all reads done before next
        asm volatile("" ::: "memory");           // iteration's STAGE overwrites
    }

#pragma unroll
    for (int n = 0; n < 4; ++n) {
        const int col = n0 + (wn << 6) + (n << 4) + l15;
        const float bvv = bias[col];
#pragma unroll
        for (int m = 0; m < 4; ++m) {
#pragma unroll
            for (int r = 0; r < 4; ++r) {
                const int row = m0 + (wm << 6) + (m << 4) + (lg << 2) + r;
                float v = acc[m][n][r] + bvv;
                if (MODE == 0)
                    v += (float)posh[((size_t)(row & 255) << 12) + col];
                if (MODE == 2)
                    Cf[((size_t)row << 12) + col] = v;
                else
                    Ch[((size_t)row << 12) + col] = (f16)v;
            }
        }
    }
}

// ---------------- f16 scores + softmax -> P fp32 (out1) + P f16 (PV) --------
// grid = 512: XCD-contiguous remap (4 q-slab blocks of one (b,h) share K).
__global__ __launch_bounds__(256)
void attn_scores(const f16* __restrict__ q, const f16* __restrict__ k,
                 float* __restrict__ Pf, f16* __restrict__ Pb) {
    const int blk = ((blockIdx.x & 7) << 6) + (blockIdx.x >> 3);  // 8 XCDs x 64
    const int bh = blk >> 2, it = blk & 3;
    const int b = bh >> 3, h = bh & 7;
    const size_t qoff = ((size_t)(b * 256 + it * 64) << 12) + (h << 9);
    const size_t koff = ((size_t)(b * 256) << 12) + (h << 9);
    __shared__ __align__(16) u16 Qs[64 * 64];
    __shared__ __align__(16) u16 Ks[256 * 64];
    __shared__ float red[4][64];

    const int t = threadIdx.x;
    const int lane = t & 63, w = t >> 6;
    const int l15 = lane & 15, lg = lane >> 4;

    vf32x4 acc[4][4] = {};

    for (int k0 = 0; k0 < 512; k0 += 64) {
#pragma unroll
        for (int i = 0; i < 2; ++i) {               // Q slab: 64x64
            const int c = t + (i << 8);
            const int row = c >> 3, c8 = (c & 7) << 3;
            gld16(q + qoff + ((size_t)row << 12) + k0 + c8, Qs + c * 8);
        }
#pragma unroll
        for (int i = 0; i < 8; ++i) {               // K: 256x64
            const int c = t + (i << 8);
            const int row = c >> 3, c8 = (c & 7) << 3;
            gld16(k + koff + ((size_t)row << 12) + k0 + c8, Ks + c * 8);
        }
        __syncthreads();
#pragma unroll
        for (int kk = 0; kk < 2; ++kk) {
            v8h af[4], bf[4];
#pragma unroll
            for (int m = 0; m < 4; ++m)
                af[m] = *(const v8h*)(Qs + (m * 16 + l15) * 64 + kk * 32 + lg * 8);
#pragma unroll
            for (int n = 0; n < 4; ++n)
                bf[n] = *(const v8h*)(Ks + (w * 64 + n * 16 + l15) * 64 + kk * 32 + lg * 8);
#pragma unroll
            for (int m = 0; m < 4; ++m)
#pragma unroll
                for (int n = 0; n < 4; ++n)
                    acc[m][n] = MFMA_F16(af[m], bf[n], acc[m][n]);
        }
        __syncthreads();
    }

#pragma unroll
    for (int m = 0; m < 4; ++m)
#pragma unroll
        for (int n = 0; n < 4; ++n) acc[m][n] *= 0.125f;

    float gm[4][4];
#pragma unroll
    for (int m = 0; m < 4; ++m)
#pragma unroll
        for (int r = 0; r < 4; ++r) {
            float v = fmaxf(fmaxf(acc[m][0][r], acc[m][1][r]),
                            fmaxf(acc[m][2][r], acc[m][3][r]));
#pragma unroll
            for (int off = 1; off < 16; off <<= 1) v = fmaxf(v, __shfl_xor(v, off));
            gm[m][r] = v;
        }
    if (l15 == 0) {
#pragma unroll
        for (int m = 0; m < 4; ++m)
#pragma unroll
            for (int r = 0; r < 4; ++r) red[w][m * 16 + lg * 4 + r] = gm[m][r];
    }
    __syncthreads();
#pragma unroll
    for (int m = 0; m < 4; ++m)
#pragma unroll
        for (int r = 0; r < 4; ++r) {
            const int row = m * 16 + lg * 4 + r;
            gm[m][r] = fmaxf(fmaxf(red[0][row], red[1][row]),
                             fmaxf(red[2][row], red[3][row]));
        }
    __syncthreads();

    float gs[4][4];
#pragma unroll
    for (int m = 0; m < 4; ++m)
#pragma unroll
        for (int r = 0; r < 4; ++r) {
            float s = 0.f;
#pragma unroll
            for (int n = 0; n < 4; ++n) {
                const float e = __expf(acc[m][n][r] - gm[m][r]);
                acc[m][n][r] = e;
                s += e;
            }
#pragma unroll
            for (int off = 1; off < 16; off <<= 1) s += __shfl_xor(s, off);
            gs[m][r] = s;
        }
    if (l15 == 0) {
#pragma unroll
        for (int m = 0; m < 4; ++m)
#pragma unroll
            for (int r = 0; r < 4; ++r) red[w][m * 16 + lg * 4 + r] = gs[m][r];
    }
    __syncthreads();

    const size_t pbase = ((size_t)bh * 256 + it * 64) * 256;
#pragma unroll
    for (int m = 0; m < 4; ++m)
#pragma unroll
        for (int r = 0; r < 4; ++r) {
            const int row = m * 16 + lg * 4 + r;
            const float inv = 1.0f / (red[0][row] + red[1][row] +
                                      red[2][row] + red[3][row]);
#pragma unroll
            for (int n = 0; n < 4; ++n) {
                const int col = w * 64 + n * 16 + l15;
                const float p = acc[m][n][r] * inv;
                Pf[pbase + (size_t)row * 256 + col] = p;
                Pb[pbase + (size_t)row * 256 + col] = (f16)p;
            }
        }
}

// ---------------- PV: ao[b,n,h*512+j] = sum_m P[b,h,n,m] * v[b,m,h*512+j] ---
__global__ __launch_bounds__(256)
void attn_pv(const f16* __restrict__ P, const f16* __restrict__ V,
             f16* __restrict__ O) {
    __shared__ __align__(16) u16 Ps[128 * 64];
    __shared__ __align__(16) u16 Vt[128 * 72];   // [j][m], padded stride 72
    const int t = threadIdx.x;
    const int lane = t & 63, w = t >> 6;
    const int wr = (w >> 1) << 6, wc = (w & 1) << 6;
    const int l15 = lane & 15, lg = lane >> 4;
    const int blk = ((blockIdx.x & 7) << 7) + (blockIdx.x >> 3);  // 8 x 128
    const int bh = blk >> 3, mt = (blk >> 2) & 1, nt = blk & 3;
    const int b = bh >> 3, h = bh & 7;
    const f16* Pbp = P + ((size_t)bh << 16) + ((size_t)mt << 15);
    const u16* Vb = (const u16*)V + ((size_t)(b * 256) << 12) + (h << 9) + (nt << 7);

    vf32x4 acc[4][4] = {};

    for (int k0 = 0; k0 < 256; k0 += 64) {
#pragma unroll
        for (int i = 0; i < 4; ++i) {               // P tile 128x64, linear
            const int c = t + (i << 8);
            const int row = c >> 3, c8 = (c & 7) << 3;
            gld16(Pbp + (size_t)row * 256 + k0 + c8, Ps + c * 8);
        }
#pragma unroll
        for (int pp = 0; pp < 4; ++pp) {            // V tile 64x128, transposed
            const int kr = pp * 16 + (t >> 4);
            const int c8 = (t & 15) << 3;
            vu16x8 vv = *(const vu16x8*)(Vb + ((size_t)(k0 + kr) << 12) + c8);
#pragma unroll
            for (int c = 0; c < 8; ++c) Vt[(c8 + c) * 72 + kr] = (u16)vv[c];
        }
        __syncthreads();
#pragma unroll
        for (int kk = 0; kk < 2; ++kk) {
            v8h af[4], bf[4];
#pragma unroll
            for (int m = 0; m < 4; ++m)
                af[m] = *(const v8h*)(Ps + (wr + m * 16 + l15) * 64 + kk * 32 + lg * 8);
#pragma unroll
            for (int n = 0; n < 4; ++n)
                bf[n] = *(const v8h*)(Vt + (wc + n * 16 + l15) * 72 + kk * 32 + lg * 8);
#pragma unroll
            for (int m = 0; m < 4; ++m)
#pragma unroll
                for (int n = 0; n < 4; ++n)
                    acc[m][n] = MFMA_F16(af[m], bf[n], acc[m][n]);
        }
        __syncthreads();
    }

#pragma unroll
    for (int m = 0; m < 4; ++m)
#pragma unroll
        for (int n = 0; n < 4; ++n) {
            const int col = (h << 9) + (nt << 7) + wc + n * 16 + l15;
#pragma unroll
            for (int r = 0; r < 4; ++r) {
                const int row = b * 256 + mt * 128 + wr + m * 16 + lg * 4 + r;
                O[((size_t)row << 12) + col] = (f16)acc[m][n][r];
            }
        }
}

// ---------------------------------------------------------------------------
extern "C" void kernel_launch(void* const* d_in, const int* in_sizes, int n_in,
                              void* d_out, int out_size, void* d_ws, size_t ws_size,
                              hipStream_t stream) {
    const float* x   = (const float*)d_in[0];
    const float* pos = (const float*)d_in[1];
    const float* wE  = (const float*)d_in[2];
    const float* bE  = (const float*)d_in[3];
    const float* wQ  = (const float*)d_in[4];
    const float* bq  = (const float*)d_in[5];
    const float* wK  = (const float*)d_in[6];
    const float* bk  = (const float*)d_in[7];
    const float* wV  = (const float*)d_in[8];
    const float* bv  = (const float*)d_in[9];
    const float* wO  = (const float*)d_in[10];
    const float* bo  = (const float*)d_in[11];

    float* out  = (float*)d_out;                    // output 0: 16,777,216 fp32
    float* Pout = out + (size_t)16777216;           // output 1:  8,388,608 fp32

    // ws layout (MiB offsets), peak 212 MiB
    char* W = (char*)d_ws;
    const size_t MB = 1024 * 1024;
    f16* xf    = (f16*)(W + 0 * MB);     // x f16; later ao (x dead post-embed)
    f16* wslab = (f16*)(W + 32 * MB);    // current weight f16
    f16* xe    = (f16*)(W + 64 * MB);    // embedded activations f16
    f16* qs    = (f16*)(W + 96 * MB);    // Q f16
    f16* ks    = (f16*)(W + 128 * MB);   // K f16
    f16* vs    = (f16*)(W + 160 * MB);   // V f16
    f16* Pb    = (f16*)(W + 192 * MB);   // P f16 (16 MiB)
    f16* posh  = (f16*)(W + 208 * MB);   // pos f16 (2 MiB)
    f16* ao    = xf;                     // PV result over x (dead)

    const int CVG = 16384;   // 16.7M elems / (256 thr * 4/thread)
    const int CVP = 1024;    // 1,048,576 pos elems / (256 * 4)

    tof16<<<CVP, 256, 0, stream>>>(pos, posh);
    tof16<<<CVG, 256, 0, stream>>>(x, xf);
    tof16<<<CVG, 256, 0, stream>>>(wE, wslab);
    gemm4_nt<0><<<512, 512, 0, stream>>>(xf, wslab, bE, posh, xe, nullptr);

    tof16<<<CVG, 256, 0, stream>>>(wQ, wslab);
    gemm4_nt<1><<<512, 512, 0, stream>>>(xe, wslab, bq, nullptr, qs, nullptr);

    tof16<<<CVG, 256, 0, stream>>>(wK, wslab);
    gemm4_nt<1><<<512, 512, 0, stream>>>(xe, wslab, bk, nullptr, ks, nullptr);

    tof16<<<CVG, 256, 0, stream>>>(wV, wslab);
    gemm4_nt<1><<<512, 512, 0, stream>>>(xe, wslab, bv, nullptr, vs, nullptr);

    attn_scores<<<512, 256, 0, stream>>>(qs, ks, Pout, Pb);
    attn_pv<<<1024, 256, 0, stream>>>(Pb, vs, ao);

    tof16<<<CVG, 256, 0, stream>>>(wO, wslab);
    gemm4_nt<2><<<512, 512, 0, stream>>>(ao, wslab, bo, nullptr, nullptr, out);
}